// Round 4
// baseline (399.106 us; speedup 1.0000x reference)
//
#include <hip/hip_runtime.h>
#include <hip/hip_fp16.h>
#include <math.h>

// ---------------------------------------------------------------------------
// GAT 2-layer forward. Pipeline:
//   0) detect edge_index dtype (int32 vs int64) on-device
//   1) CSR build by target: histogram -> scan -> scatter  (reused by both layers)
//   2) gemm1: proj1(fp16) = x @ W1^T  (+ fused s_src1/s_trg1 head logits, fp32)
//   3) agg1 : per-target softmax over incoming edges + weighted sum + ELU -> h1(fp16)
//   4) gemm2: proj2 = h1 @ W2^T  (+ fused s_src2/s_trg2)
//   5) agg2 : per-target softmax-attention + bias + row-softmax -> out
// Workspace ~25.0 MB.
// ---------------------------------------------------------------------------

__device__ __forceinline__ float leaky02(float v){ return v > 0.f ? v : 0.2f*v; }
// exp with cap; cap is inert for sane logits (|logit| <~ 15 here)
__device__ __forceinline__ float expc(float v){ return __expf(fminf(v, 60.f)); }

// read edge id at flat index idx under either dtype
__device__ __forceinline__ int edge_at(const void* ei, int isI32, long long idx){
  if (isI32) return ((const int*)ei)[idx];
  return (int)((const long long*)ei)[idx];
}

// ---------------- edge dtype detection ----------------
// OR all odd 32-bit words among the first 2E words (safe under both layouts).
// int64 edges (values in [0, 50000)): those are high words -> all 0.
// int32 edges: those are real edge ids -> some nonzero (certain at E=1.6M).
__global__ void k_detect(const unsigned int* __restrict__ w, int nwords, int* __restrict__ flag){
  int gid = blockIdx.x*256 + threadIdx.x;
  int stride = gridDim.x*256;
  unsigned int v = 0;
  for (int idx = 2*gid + 1; idx < nwords; idx += 2*stride)
    v |= w[idx];
  unsigned long long b = __ballot(v != 0);
  if ((threadIdx.x & 63) == 0 && b != 0ULL) atomicOr(flag, 1);
}

// ---------------- CSR build ----------------
__global__ void k_hist(const void* __restrict__ ei, const int* __restrict__ flag,
                       int* __restrict__ counts, int E, int N){
  int e = blockIdx.x*256 + threadIdx.x;
  if (e < E){
    int t = edge_at(ei, *flag, (long long)e + E);
    t = min(max(t, 0), N-1);
    atomicAdd(&counts[t], 1);
  }
}

// block scans 1024 elements (256 thr x 4), writes per-element inclusive + block sum
__global__ void k_scan1(const int* __restrict__ counts, int* __restrict__ temp,
                        int* __restrict__ partials, int n){
  __shared__ int lds[256];
  int tid = threadIdx.x;
  int base = blockIdx.x*1024 + tid*4;
  int a0 = (base+0 < n) ? counts[base+0] : 0;
  int a1 = (base+1 < n) ? counts[base+1] : 0;
  int a2 = (base+2 < n) ? counts[base+2] : 0;
  int a3 = (base+3 < n) ? counts[base+3] : 0;
  int p1 = a0+a1, p2 = p1+a2, p3 = p2+a3;
  lds[tid] = p3; __syncthreads();
  for (int s=1; s<256; s<<=1){
    int v = (tid>=s) ? lds[tid-s] : 0;
    __syncthreads();
    lds[tid] += v;
    __syncthreads();
  }
  int excl = lds[tid] - p3;
  if (base+0 < n) temp[base+0] = excl + a0;
  if (base+1 < n) temp[base+1] = excl + p1;
  if (base+2 < n) temp[base+2] = excl + p2;
  if (base+3 < n) temp[base+3] = excl + p3;
  if (tid == 255) partials[blockIdx.x] = lds[255];
}

// single wave scans <=64 block sums in place -> exclusive
__global__ void k_scan2(int* __restrict__ partials, int nb){
  int lane = threadIdx.x;
  int v = (lane < nb) ? partials[lane] : 0;
  int orig = v;
  for (int s=1; s<64; s<<=1){
    int u = __shfl_up(v, s);
    if (lane >= s) v += u;
  }
  if (lane < nb) partials[lane] = v - orig;
}

__global__ void k_scan3(const int* __restrict__ temp, const int* __restrict__ partials,
                        const int* __restrict__ counts, int* __restrict__ offsets,
                        int* __restrict__ cursor, int n){
  int tid = threadIdx.x;
  int base = blockIdx.x*1024 + tid*4;
  int add = partials[blockIdx.x];
  #pragma unroll
  for (int j=0; j<4; ++j){
    int i = base + j;
    if (i < n){
      int incl = temp[i] + add;
      offsets[i+1] = incl;             // offsets[t+1] = prefix including t
      cursor[i]    = incl - counts[i]; // exclusive prefix = segment start
    }
  }
  if (blockIdx.x == 0 && tid == 0) offsets[0] = 0;
}

__global__ void k_scatter(const void* __restrict__ ei, const int* __restrict__ flag,
                          int* __restrict__ cursor, int* __restrict__ sorted, int E, int N){
  int e = blockIdx.x*256 + threadIdx.x;
  if (e < E){
    int f = *flag;
    int s = edge_at(ei, f, (long long)e);
    int t = edge_at(ei, f, (long long)e + E);
    s = min(max(s, 0), N-1);
    t = min(max(t, 0), N-1);
    int pos = atomicAdd(&cursor[t], 1);
    sorted[pos] = s;
  }
}

// ---------------- layer 1 projection: proj1 = x @ W1^T, fused s_src1/s_trg1 ----------------
// 64 rows x 64 cols tile, 16x16 threads, 4x4 microtile. K=128 staged in two
// 64-wide halves so static LDS = 34,816 B.
__global__ __launch_bounds__(256) void k_gemm1(
    const float* __restrict__ x, const float* __restrict__ W,
    const float* __restrict__ a_src, const float* __restrict__ a_trg,
    __half* __restrict__ proj, float* __restrict__ s_src, float* __restrict__ s_trg, int n){
  const int PAD = 68;
  __shared__ float xsT[64*PAD];  // [k][row], one K-half
  __shared__ float wT [64*PAD];  // [k][col], one K-half
  int tid = threadIdx.x;
  int n0  = blockIdx.x*64;
  int tn = tid & 15, tm = tid >> 4;
  const float4* x4 = (const float4*)x;
  float acc[4][4] = {};

  for (int kh = 0; kh < 2; ++kh){
    __syncthreads();   // protect previous half's reads before overwrite
    // stage W half: wT[k][c] = W[c*128 + kh*64 + k]
    #pragma unroll
    for (int it=0; it<16; ++it){
      int idx = it*256 + tid;
      int c = idx >> 6, k = idx & 63;
      wT[k*PAD + c] = W[c*128 + kh*64 + k];
    }
    // stage x half (float4 global reads): xsT[4*k4+j][r] = x[(n0+r)*128 + kh*64 + 4*k4+j]
    #pragma unroll
    for (int it=0; it<4; ++it){
      int idx = it*256 + tid;
      int r = idx >> 4, k4 = idx & 15;
      int row = n0 + r;
      float4 v = (row < n) ? x4[(size_t)row*32 + kh*16 + k4] : make_float4(0.f,0.f,0.f,0.f);
      xsT[(k4*4+0)*PAD + r] = v.x;
      xsT[(k4*4+1)*PAD + r] = v.y;
      xsT[(k4*4+2)*PAD + r] = v.z;
      xsT[(k4*4+3)*PAD + r] = v.w;
    }
    __syncthreads();

    #pragma unroll 8
    for (int k=0; k<64; ++k){
      float4 av = *(const float4*)&xsT[k*PAD + tm*4];
      float4 bv = *(const float4*)&wT [k*PAD + tn*4];
      float a_[4] = {av.x, av.y, av.z, av.w};
      float b_[4] = {bv.x, bv.y, bv.z, bv.w};
      #pragma unroll
      for (int i=0;i<4;++i)
        #pragma unroll
        for (int j=0;j<4;++j)
          acc[i][j] += a_[i]*b_[j];
    }
  }

  // fused epilogue: write proj(fp16) + head logits (head = tn>>1, pair via shfl)
  float as[4], at[4];
  #pragma unroll
  for (int j=0;j<4;++j){ as[j] = a_src[tn*4+j]; at[j] = a_trg[tn*4+j]; }
  #pragma unroll
  for (int i=0;i<4;++i){
    int row = n0 + tm*4 + i;
    float ps = 0.f, pt = 0.f;
    #pragma unroll
    for (int j=0;j<4;++j){ ps += acc[i][j]*as[j]; pt += acc[i][j]*at[j]; }
    ps += __shfl_xor(ps, 1);
    pt += __shfl_xor(pt, 1);
    if (row < n){
      __half* pr = proj + (size_t)row*64 + tn*4;
      #pragma unroll
      for (int j=0;j<4;++j) pr[j] = __float2half(acc[i][j]);
      if ((tn & 1) == 0){
        s_src[row*8 + (tn>>1)] = ps;
        s_trg[row*8 + (tn>>1)] = pt;
      }
    }
  }
}

// ---------------- layer 1 aggregation: one wave per target node ----------------
__global__ __launch_bounds__(64) void k_agg1(
    const int* __restrict__ off, const int* __restrict__ srcs,
    const float* __restrict__ ss, const float* __restrict__ st,
    const __half* __restrict__ proj, const float* __restrict__ b1,
    __half* __restrict__ hout, int N){
  int t = blockIdx.x;
  int lane = threadIdx.x;
  int start = off[t], end = off[t+1];

  // pass 1: per-head exp-sum. lanes = 8 edge-groups x 8 heads
  int hh = lane & 7, g = lane >> 3;
  float st1 = st[t*8 + hh];
  float part = 0.f;
  for (int e = start + g; e < end; e += 8){
    int s = min(max(srcs[e], 0), N-1);
    float v = ss[s*8 + hh] + st1;
    part += expc(leaky02(v));
  }
  part += __shfl_xor(part, 8);
  part += __shfl_xor(part, 16);
  part += __shfl_xor(part, 32);      // every lane: denom for head (lane&7)

  // pass 2: lane owns output component c=lane (head = lane>>3, f = lane&7)
  int h2 = lane >> 3;
  float denom = __shfl(part, h2);    // denom for head h2
  float rd = 1.f / (denom + 1e-16f);
  float st2 = st[t*8 + h2];
  float acc = 0.f;
  for (int e = start; e < end; ++e){
    int s = min(max(srcs[e], 0), N-1);
    float v = ss[s*8 + h2] + st2;
    float w = expc(leaky02(v)) * rd;
    acc += w * __half2float(proj[(size_t)s*64 + lane]);
  }
  float z = acc + b1[lane];
  hout[(size_t)t*64 + lane] = __float2half((z > 0.f) ? z : expm1f(z));  // ELU
}

// ---------------- layer 2 projection: proj2 = h @ W2^T, fused s2 ----------------
__global__ __launch_bounds__(256) void k_gemm2(
    const __half* __restrict__ h, const float* __restrict__ W2,
    const float* __restrict__ a_src2, const float* __restrict__ a_trg2,
    float* __restrict__ proj2, float* __restrict__ ssrc2, float* __restrict__ strg2, int n){
  __shared__ float wl[7*68];
  int tid = threadIdx.x;
  for (int i = tid; i < 7*64; i += 256){     // FIX: full 448-element stage
    int f = i >> 6, k = i & 63;
    wl[f*68 + k] = W2[i];
  }
  __syncthreads();
  int f = tid & 7, ln = tid >> 3;
  int node = blockIdx.x*32 + ln;
  int fe = (f < 7) ? f : 6;
  float acc = 0.f;
  if (node < n){
    const __half* hp = h + (size_t)node*64;
    #pragma unroll
    for (int k=0; k<64; ++k)
      acc += __half2float(hp[k]) * wl[fe*68 + k];
  }
  float vs = (f < 7) ? acc * a_src2[f] : 0.f;
  float vt = (f < 7) ? acc * a_trg2[f] : 0.f;
  vs += __shfl_xor(vs,1); vt += __shfl_xor(vt,1);
  vs += __shfl_xor(vs,2); vt += __shfl_xor(vt,2);
  vs += __shfl_xor(vs,4); vt += __shfl_xor(vt,4);
  if (node < n){
    if (f < 7) proj2[(size_t)node*7 + f] = acc;
    if (f == 0){ ssrc2[node] = vs; strg2[node] = vt; }
  }
}

// ---------------- layer 2 aggregation + final softmax ----------------
__global__ __launch_bounds__(64) void k_agg2(
    const int* __restrict__ off, const int* __restrict__ srcs,
    const float* __restrict__ ss, const float* __restrict__ st,
    const float* __restrict__ proj2, const float* __restrict__ b2,
    float* __restrict__ out, int N){
  int t = blockIdx.x;
  int lane = threadIdx.x;
  int start = off[t], end = off[t+1];
  float stv = st[t];

  // pass 1: denominator (all 64 lanes over edges)
  float p = 0.f;
  for (int e = start + lane; e < end; e += 64){
    int s = min(max(srcs[e], 0), N-1);
    p += expc(leaky02(ss[s] + stv));
  }
  #pragma unroll
  for (int sdx=1; sdx<64; sdx<<=1) p += __shfl_xor(p, sdx);
  float rd = 1.f / (p + 1e-16f);

  // pass 2: 8 edge-groups x 8 feature slots (f<7 valid)
  int f = lane & 7, g = lane >> 3;
  int fe = (f < 7) ? f : 6;
  float acc = 0.f;
  for (int e = start + g; e < end; e += 8){
    int s = min(max(srcs[e], 0), N-1);
    float w = expc(leaky02(ss[s] + stv)) * rd;
    acc += w * proj2[(size_t)s*7 + fe];
  }
  acc += __shfl_xor(acc, 8);
  acc += __shfl_xor(acc, 16);
  acc += __shfl_xor(acc, 32);        // all lanes: z for f = lane&7

  float z = (f < 7) ? acc + b2[f] : -3.0e38f;
  float m = z;
  m = fmaxf(m, __shfl_xor(m, 1));
  m = fmaxf(m, __shfl_xor(m, 2));
  m = fmaxf(m, __shfl_xor(m, 4));
  float ev = (f < 7) ? __expf(z - m) : 0.f;
  float sum = ev;
  sum += __shfl_xor(sum, 1);
  sum += __shfl_xor(sum, 2);
  sum += __shfl_xor(sum, 4);
  if (lane < 7) out[(size_t)t*7 + lane] = ev / sum;
}

// ---------------------------------------------------------------------------
extern "C" void kernel_launch(void* const* d_in, const int* in_sizes, int n_in,
                              void* d_out, int out_size, void* d_ws, size_t ws_size,
                              hipStream_t stream){
  int N = in_sizes[0] / 128;
  int E = in_sizes[1] / 2;
  const float* x   = (const float*)d_in[0];
  const void*  ei  = d_in[1];
  const float* W1  = (const float*)d_in[2];
  const float* as1 = (const float*)d_in[3];
  const float* at1 = (const float*)d_in[4];
  const float* b1  = (const float*)d_in[5];
  const float* W2  = (const float*)d_in[6];
  const float* as2 = (const float*)d_in[7];
  const float* at2 = (const float*)d_in[8];
  const float* b2  = (const float*)d_in[9];
  float* out = (float*)d_out;

  auto aln = [](size_t v){ return (v + 255) & ~(size_t)255; };
  char* w = (char*)d_ws;
  int* flag     = (int*)w; w += aln(4);
  int* counts   = (int*)w; w += aln((size_t)N*4);
  int* temp     = (int*)w; w += aln((size_t)N*4);
  int* partials = (int*)w; w += aln(256*4);
  int* offsets  = (int*)w; w += aln((size_t)(N+1)*4);
  int* cursor   = (int*)w; w += aln((size_t)N*4);
  int* sorted   = (int*)w; w += aln((size_t)E*4);
  __half* proj1 = (__half*)w; w += aln((size_t)N*64*2);
  float* ssrc1  = (float*)w; w += aln((size_t)N*8*4);
  float* strg1  = (float*)w; w += aln((size_t)N*8*4);
  __half* h1    = (__half*)w; w += aln((size_t)N*64*2);
  float* proj2  = (float*)w; w += aln((size_t)N*7*4 + 64);
  float* ssrc2  = (float*)w; w += aln((size_t)N*4);
  float* strg2  = (float*)w; w += aln((size_t)N*4);

  hipMemsetAsync(flag, 0, 4, stream);
  hipMemsetAsync(counts, 0, (size_t)N*4, stream);

  int eb = (E + 255) / 256;
  int nb = (N + 1023) / 1024;

  k_detect <<<512, 256, 0, stream>>>((const unsigned int*)ei, 2*E, flag);

  k_hist   <<<eb, 256, 0, stream>>>(ei, flag, counts, E, N);
  k_scan1  <<<nb, 256, 0, stream>>>(counts, temp, partials, N);
  k_scan2  <<<1,  64,  0, stream>>>(partials, nb);
  k_scan3  <<<nb, 256, 0, stream>>>(temp, partials, counts, offsets, cursor, N);
  k_scatter<<<eb, 256, 0, stream>>>(ei, flag, cursor, sorted, E, N);

  k_gemm1<<<(N+63)/64, 256, 0, stream>>>(x, W1, as1, at1, proj1, ssrc1, strg1, N);
  k_agg1 <<<N, 64, 0, stream>>>(offsets, sorted, ssrc1, strg1, proj1, b1, h1, N);
  k_gemm2<<<(N+31)/32, 256, 0, stream>>>(h1, W2, as2, at2, proj2, ssrc2, strg2, N);
  k_agg2 <<<N, 64, 0, stream>>>(offsets, sorted, ssrc2, strg2, proj2, b2, out, N);
}